// Round 6
// baseline (123.323 us; speedup 1.0000x reference)
//
#include <hip/hip_runtime.h>

// AttentionConvFull: grouped 1x1 QKV + 5x5 per-channel local attention.
// B=4, H=W=56, C=OC=256, G=8, Cg=32, K=5, pad=2.
//
// K1 (qkv):  LDS-staged x strip; 2-pass (k&v, then q) so live weight regs fit
//            the (256,4) cap-64 budget (R2 measured VGPR=56, no spill).
//            Bulk float4 staging gives full MLP on the HBM-cold x read.
// K2 (attn): k,v halo (12x12x32) in LDS; row-streaming 5-wide window; native
//            exp2/rcp; single-pass softmax (logits bounded, f32-safe).
//
// Register-budget law (R1-R5): VGPR cap = 256/N for __launch_bounds__(256,N);
// NO launch_bounds also caps at 64. Exceeding the cap spills to scratch ->
// shows up as inflated FETCH/WRITE_SIZE + ~5-10x slowdown (R3/R4).
// R5 lesson: asm-pinning registers under a tight cap forces liveness -> spill
// (attn WRITE 24MB vs 12.8MB output). Occupancy beats per-thread efficiency
// for this latency-bound op (R2's cap-64 LDS qkv 2x faster than 96-reg no-LDS).

constexpr int TB = 4, TH = 56, TW = 56, TC = 256;
constexpr int G  = 8, CG = 32, PAD = 2;
constexpr int TILE = 8;
constexpr int HT = TILE + 2 * PAD;   // 12
constexpr int NT = TH / TILE;        // 7
constexpr int NPIX_HALO = HT * HT;   // 144
constexpr float LOG2E = 1.44269504088896340736f;

// ---------------- Kernel 1: QKV projection (LDS-staged, 2-pass) ----------------
constexpr int PPB = 16;   // pixels per block

__global__ __launch_bounds__(256, 4)
void qkv_kernel(const float* __restrict__ x,
                const float* __restrict__ wq,
                const float* __restrict__ wk,
                const float* __restrict__ wv,
                const float* __restrict__ qemb,
                float* __restrict__ qm, float* __restrict__ km,
                float* __restrict__ vm) {
    __shared__ float xs[PPB][TC];   // 16 KB
    const int t = threadIdx.x;
    const size_t base = (size_t)blockIdx.x * PPB * TC;

    // coalesced float4 staging of the 16-pixel strip (4096 floats = 1024 float4)
    {
        const float4* xg = (const float4*)(x + base);
        float4* xsv = (float4*)&xs[0][0];
#pragma unroll
        for (int i = 0; i < 4; ++i)
            xsv[t + i * 256] = xg[t + i * 256];
    }

    const int c = t;          // output channel 0..255
    const int g = c >> 5;
    __syncthreads();

    // ---- pass 1: k and v (64 weight regs live)
    {
        float wkr[CG], wvr[CG];
        const float4* wkp = (const float4*)(wk + (size_t)c * CG);
        const float4* wvp = (const float4*)(wv + (size_t)c * CG);
#pragma unroll
        for (int i = 0; i < CG / 4; ++i) {
            float4 bb = wkp[i], cc = wvp[i];
            wkr[4*i+0]=bb.x; wkr[4*i+1]=bb.y; wkr[4*i+2]=bb.z; wkr[4*i+3]=bb.w;
            wvr[4*i+0]=cc.x; wvr[4*i+1]=cc.y; wvr[4*i+2]=cc.z; wvr[4*i+3]=cc.w;
        }
#pragma unroll 2
        for (int p = 0; p < PPB; ++p) {
            const float4* xp = (const float4*)&xs[p][g * CG];
            float ak = 0.f, av = 0.f;
#pragma unroll
            for (int i = 0; i < CG / 4; ++i) {
                const float4 xv = xp[i];
                ak = fmaf(wkr[4*i+0], xv.x, ak); av = fmaf(wvr[4*i+0], xv.x, av);
                ak = fmaf(wkr[4*i+1], xv.y, ak); av = fmaf(wvr[4*i+1], xv.y, av);
                ak = fmaf(wkr[4*i+2], xv.z, ak); av = fmaf(wvr[4*i+2], xv.z, av);
                ak = fmaf(wkr[4*i+3], xv.w, ak); av = fmaf(wvr[4*i+3], xv.w, av);
            }
            km[base + p * TC + c] = ak;
            vm[base + p * TC + c] = av;
        }
    }

    // ---- pass 2: q (+q_emb), pre-scaled by log2(e) for exp2-based softmax
    {
        float wqr[CG];
        const float4* wqp = (const float4*)(wq + (size_t)c * CG);
#pragma unroll
        for (int i = 0; i < CG / 4; ++i) {
            float4 a = wqp[i];
            wqr[4*i+0]=a.x; wqr[4*i+1]=a.y; wqr[4*i+2]=a.z; wqr[4*i+3]=a.w;
        }
        const float qe = qemb[c];
#pragma unroll 2
        for (int p = 0; p < PPB; ++p) {
            const float4* xp = (const float4*)&xs[p][g * CG];
            float aq = qe;
#pragma unroll
            for (int i = 0; i < CG / 4; ++i) {
                const float4 xv = xp[i];
                aq = fmaf(wqr[4*i+0], xv.x, aq);
                aq = fmaf(wqr[4*i+1], xv.y, aq);
                aq = fmaf(wqr[4*i+2], xv.z, aq);
                aq = fmaf(wqr[4*i+3], xv.w, aq);
            }
            qm[base + p * TC + c] = aq * LOG2E;
        }
    }
}

// ---------------- Kernel 2: local attention ----------------
__global__ __launch_bounds__(256, 2)
void attn_kernel(const float* __restrict__ qm,
                 const float* __restrict__ km,
                 const float* __restrict__ vm,
                 const float* __restrict__ rel,
                 float* __restrict__ out) {
    __shared__ float ks[NPIX_HALO][CG];   // 18 KB
    __shared__ float vs[NPIX_HALO][CG];   // 18 KB

    const int bid  = blockIdx.x;
    const int g    = bid & 7;
    const int tile = bid >> 3;
    const int tj   = tile % NT;
    const int ti   = (tile / NT) % NT;
    const int b    = tile / (NT * NT);

    const int t  = threadIdx.x;
    const int c  = t & 31;
    const int p0 = t >> 5;

    // stage k,v halo with float4: 8 lanes cover one pixel's 32 channels
    const int c4 = t & 7, pp = t >> 3;   // pp: 0..31
    const int h0 = ti * TILE - PAD, w0 = tj * TILE - PAD;
#pragma unroll
    for (int it = 0; it < 5; ++it) {
        const int hp = pp + it * 32;
        if (hp < NPIX_HALO) {
            const int hi = hp / HT, hj = hp % HT;
            const int gh = h0 + hi, gw = w0 + hj;
            float4 kv = make_float4(0.f, 0.f, 0.f, 0.f);
            float4 vv = kv;
            if (gh >= 0 && gh < TH && gw >= 0 && gw < TW) {
                const size_t off = (((size_t)b * TH + gh) * TW + gw) * TC + g * CG + c4 * 4;
                kv = *(const float4*)(km + off);
                vv = *(const float4*)(vm + off);
            }
            *(float4*)&ks[hp][c4 * 4] = kv;
            *(float4*)&vs[hp][c4 * 4] = vv;
        }
    }

    // q (already *log2e) for this thread's 8 interior pixels (column p0)
    float qreg[8];
#pragma unroll
    for (int ii = 0; ii < 8; ++ii) {
        const int gh = ti * TILE + ii, gw = tj * TILE + p0;
        qreg[ii] = qm[(((size_t)b * TH + gh) * TW + gw) * TC + g * CG + c];
    }

    // rel row for this channel from global (L1/L2-hot; compiler-managed regs —
    // NO asm pins: R5 showed pinning under the cap forces spill)
    const float* rp = rel + ((size_t)g * CG + c) * 25;
    float relr[25];
#pragma unroll
    for (int i = 0; i < 25; ++i) relr[i] = rp[i];

    __syncthreads();

    // ---- row-streaming attention: each halo row's 5 k/v values loaded once,
    //      scattered into the (up to 5) output pixels whose window covers it.
    float s_[8], a_[8];
#pragma unroll
    for (int ii = 0; ii < 8; ++ii) { s_[ii] = 0.f; a_[ii] = 0.f; }

#pragma unroll
    for (int h = 0; h < HT; ++h) {
        float kr[5], vr[5];
#pragma unroll
        for (int j = 0; j < 5; ++j) {
            kr[j] = ks[h * HT + p0 + j][c];
            vr[j] = vs[h * HT + p0 + j][c];
        }
#pragma unroll
        for (int ii = 0; ii < 8; ++ii) {
            const int di = h - ii;               // compile-time after unroll
            if (di >= 0 && di < 5) {
                const float qv = qreg[ii];
#pragma unroll
                for (int j = 0; j < 5; ++j) {
                    const float e = __builtin_amdgcn_exp2f(qv * (kr[j] + relr[di * 5 + j]));
                    s_[ii] += e;
                    a_[ii] = fmaf(e, vr[j], a_[ii]);
                }
            }
        }
    }

#pragma unroll
    for (int ii = 0; ii < 8; ++ii) {
        const int gh = ti * TILE + ii, gw = tj * TILE + p0;
        out[(((size_t)b * TH + gh) * TW + gw) * TC + g * CG + c] =
            a_[ii] * __builtin_amdgcn_rcpf(s_[ii]);
    }
}

// ---------------- Fallback (ws too small): fused single kernel ----------------
__global__ __launch_bounds__(256, 2)
void attn_conv_full_kernel(const float* __restrict__ x,
                           const float* __restrict__ wq,
                           const float* __restrict__ wk,
                           const float* __restrict__ wv,
                           const float* __restrict__ rel,
                           const float* __restrict__ qemb,
                           float* __restrict__ out) {
    __shared__ float xs[NPIX_HALO][CG];
    __shared__ float ks[NPIX_HALO][CG];
    __shared__ float vs[NPIX_HALO][CG];
    __shared__ float rels[CG][25];

    const int bid  = blockIdx.x;
    const int g    = bid & 7;
    const int tile = bid >> 3;
    const int tj   = tile % NT;
    const int ti   = (tile / NT) % NT;
    const int b    = tile / (NT * NT);

    const int t  = threadIdx.x;
    const int c  = t & 31;
    const int p0 = t >> 5;

    for (int i = t; i < CG * 25; i += 256)
        rels[i / 25][i % 25] = rel[g * CG * 25 + i];

    const int h0 = ti * TILE - PAD, w0 = tj * TILE - PAD;
    for (int it = 0; it < NPIX_HALO / 8; ++it) {
        const int hp = p0 + it * 8;
        const int hi = hp / HT, hj = hp % HT;
        const int gh = h0 + hi, gw = w0 + hj;
        float val = 0.f;
        if (gh >= 0 && gh < TH && gw >= 0 && gw < TW)
            val = x[(((size_t)b * TH + gh) * TW + gw) * TC + g * CG + c];
        xs[hp][c] = val;
    }

    float wqr[CG], wkr[CG], wvr[CG];
    {
        const float* wqp = wq + (size_t)(g * CG + c) * CG;
        const float* wkp = wk + (size_t)(g * CG + c) * CG;
        const float* wvp = wv + (size_t)(g * CG + c) * CG;
#pragma unroll
        for (int i = 0; i < CG; ++i) { wqr[i] = wqp[i]; wkr[i] = wkp[i]; wvr[i] = wvp[i]; }
    }
    const float qe = qemb[g * CG + c];
    __syncthreads();

    for (int it = 0; it < NPIX_HALO / 8; ++it) {
        const int hp = p0 + it * 8;
        const float4* xp = (const float4*)&xs[hp][0];
        float acck = 0.f, accv = 0.f;
#pragma unroll
        for (int i4 = 0; i4 < CG / 4; ++i4) {
            const float4 xv = xp[i4];
            acck += wkr[4*i4+0]*xv.x; accv += wvr[4*i4+0]*xv.x;
            acck += wkr[4*i4+1]*xv.y; accv += wvr[4*i4+1]*xv.y;
            acck += wkr[4*i4+2]*xv.z; accv += wvr[4*i4+2]*xv.z;
            acck += wkr[4*i4+3]*xv.w; accv += wvr[4*i4+3]*xv.w;
        }
        ks[hp][c] = acck;
        vs[hp][c] = accv;
    }

    float qreg[8];
#pragma unroll
    for (int it = 0; it < 8; ++it) {
        const int hp = (it + PAD) * HT + (p0 + PAD);
        const float4* xp = (const float4*)&xs[hp][0];
        float acc = qe;
#pragma unroll
        for (int i4 = 0; i4 < CG / 4; ++i4) {
            const float4 xv = xp[i4];
            acc += wqr[4*i4+0]*xv.x + wqr[4*i4+1]*xv.y
                 + wqr[4*i4+2]*xv.z + wqr[4*i4+3]*xv.w;
        }
        qreg[it] = acc;
    }
    __syncthreads();

    float relr[25];
#pragma unroll
    for (int i = 0; i < 25; ++i) relr[i] = rels[c][i];

#pragma unroll
    for (int it = 0; it < 8; ++it) {
        const float qv = qreg[it] * LOG2E;
        float s = 0.f, acc = 0.f;
#pragma unroll
        for (int di = 0; di < 5; ++di)
#pragma unroll
            for (int dj = 0; dj < 5; ++dj) {
                const int hp = (it + di) * HT + (p0 + dj);
                const float e = __builtin_amdgcn_exp2f(qv * (ks[hp][c] + relr[di * 5 + dj]));
                s   += e;
                acc  = fmaf(e, vs[hp][c], acc);
            }
        const int gh = ti * TILE + it, gw = tj * TILE + p0;
        out[(((size_t)b * TH + gh) * TW + gw) * TC + g * CG + c] =
            acc * __builtin_amdgcn_rcpf(s);
    }
}

extern "C" void kernel_launch(void* const* d_in, const int* in_sizes, int n_in,
                              void* d_out, int out_size, void* d_ws, size_t ws_size,
                              hipStream_t stream) {
    const float* x    = (const float*)d_in[0];
    const float* wq   = (const float*)d_in[1];
    const float* wk   = (const float*)d_in[2];
    const float* wv   = (const float*)d_in[3];
    const float* rel  = (const float*)d_in[4];
    const float* qemb = (const float*)d_in[5];
    float* out = (float*)d_out;

    const size_t npix_tot  = (size_t)TB * TH * TW;        // 12544
    const size_t map_elems = npix_tot * TC;               // 3,211,264
    const size_t need = 3 * map_elems * sizeof(float);    // ~38.6 MB

    if (ws_size >= need) {
        float* qmap = (float*)d_ws;
        float* kmap = qmap + map_elems;
        float* vmap = kmap + map_elems;
        hipLaunchKernelGGL(qkv_kernel, dim3(npix_tot / PPB), dim3(256), 0, stream,
                           x, wq, wk, wv, qemb, qmap, kmap, vmap);
        hipLaunchKernelGGL(attn_kernel, dim3(TB * NT * NT * G), dim3(256), 0, stream,
                           qmap, kmap, vmap, rel, out);
    } else {
        hipLaunchKernelGGL(attn_conv_full_kernel, dim3(TB * NT * NT * G), dim3(256), 0, stream,
                           x, wq, wk, wv, rel, qemb, out);
    }
}

// Round 7
// 62.727 us; speedup vs baseline: 1.9660x; 1.9660x over previous
//
#include <hip/hip_runtime.h>

// AttentionConvFull: grouped 1x1 QKV + 5x5 per-channel local attention.
// B=4, H=W=56, C=OC=256, G=8, Cg=32, K=5, pad=2.
//
// K1 (qkv):  LDS-staged x strip; SINGLE pass, 3 interleaved FMA chains
//            (aq/ak/av) with 96 weight regs under (256,2) [cap 128; R5's
//            no-LDS variant measured VGPR=120 with the same register set].
//            #pragma unroll 1 on the pixel loop keeps liveness flat.
// K2 (attn): k,v halo (12x12x32) in LDS; row-streaming 5-wide window; native
//            exp2/rcp; single-pass softmax (logits bounded, f32-safe).
//
// Register-budget law (R1-R6): VGPR cap = 256/N for __launch_bounds__(256,N);
// no launch_bounds ALSO caps at 64 (1024-thread default). Exceeding the cap
// spills -> inflated FETCH/WRITE_SIZE (spill traffic) + 2-10x slowdown.
// Only (256,2)/(256,1) give register-heavy kernels room. Spill signature:
// VGPR_Count == cap exactly AND WRITE_SIZE >> logical output bytes.

constexpr int TB = 4, TH = 56, TW = 56, TC = 256;
constexpr int G  = 8, CG = 32, PAD = 2;
constexpr int TILE = 8;
constexpr int HT = TILE + 2 * PAD;   // 12
constexpr int NT = TH / TILE;        // 7
constexpr int NPIX_HALO = HT * HT;   // 144
constexpr float LOG2E = 1.44269504088896340736f;

// ---------------- Kernel 1: QKV projection (LDS-staged, 1-pass, 3 chains) ----
constexpr int PPB = 16;   // pixels per block

__global__ __launch_bounds__(256, 2)
void qkv_kernel(const float* __restrict__ x,
                const float* __restrict__ wq,
                const float* __restrict__ wk,
                const float* __restrict__ wv,
                const float* __restrict__ qemb,
                float* __restrict__ qm, float* __restrict__ km,
                float* __restrict__ vm) {
    __shared__ float xs[PPB][TC];   // 16 KB
    const int t = threadIdx.x;
    const size_t base = (size_t)blockIdx.x * PPB * TC;

    // coalesced float4 staging of the 16-pixel strip (4096 floats = 1024 float4)
    {
        const float4* xg = (const float4*)(x + base);
        float4* xsv = (float4*)&xs[0][0];
#pragma unroll
        for (int i = 0; i < 4; ++i)
            xsv[t + i * 256] = xg[t + i * 256];
    }

    const int c = t;          // output channel 0..255
    const int g = c >> 5;

    // 96 weight registers: this channel's wq/wk/wv rows
    float wqr[CG], wkr[CG], wvr[CG];
    {
        const float4* wqp = (const float4*)(wq + (size_t)c * CG);
        const float4* wkp = (const float4*)(wk + (size_t)c * CG);
        const float4* wvp = (const float4*)(wv + (size_t)c * CG);
#pragma unroll
        for (int i = 0; i < CG / 4; ++i) {
            float4 a = wqp[i], bb = wkp[i], cc = wvp[i];
            wqr[4*i+0]=a.x; wqr[4*i+1]=a.y; wqr[4*i+2]=a.z; wqr[4*i+3]=a.w;
            wkr[4*i+0]=bb.x; wkr[4*i+1]=bb.y; wkr[4*i+2]=bb.z; wkr[4*i+3]=bb.w;
            wvr[4*i+0]=cc.x; wvr[4*i+1]=cc.y; wvr[4*i+2]=cc.z; wvr[4*i+3]=cc.w;
        }
    }
    const float qe = qemb[c];
    __syncthreads();

#pragma unroll 1   // keep liveness flat: auto-unroll would exceed the 128 cap
    for (int p = 0; p < PPB; ++p) {
        const float4* xp = (const float4*)&xs[p][g * CG];
        float aq = qe, ak = 0.f, av = 0.f;
#pragma unroll
        for (int i = 0; i < CG / 4; ++i) {
            const float4 xv = xp[i];
            aq = fmaf(wqr[4*i+0], xv.x, aq); ak = fmaf(wkr[4*i+0], xv.x, ak); av = fmaf(wvr[4*i+0], xv.x, av);
            aq = fmaf(wqr[4*i+1], xv.y, aq); ak = fmaf(wkr[4*i+1], xv.y, ak); av = fmaf(wvr[4*i+1], xv.y, av);
            aq = fmaf(wqr[4*i+2], xv.z, aq); ak = fmaf(wkr[4*i+2], xv.z, ak); av = fmaf(wvr[4*i+2], xv.z, av);
            aq = fmaf(wqr[4*i+3], xv.w, aq); ak = fmaf(wkr[4*i+3], xv.w, ak); av = fmaf(wvr[4*i+3], xv.w, av);
        }
        qm[base + p * TC + c] = aq * LOG2E;   // pre-scaled for exp2 softmax
        km[base + p * TC + c] = ak;
        vm[base + p * TC + c] = av;
    }
}

// ---------------- Kernel 2: local attention (R6 structure, unchanged) -------
__global__ __launch_bounds__(256, 2)
void attn_kernel(const float* __restrict__ qm,
                 const float* __restrict__ km,
                 const float* __restrict__ vm,
                 const float* __restrict__ rel,
                 float* __restrict__ out) {
    __shared__ float ks[NPIX_HALO][CG];   // 18 KB
    __shared__ float vs[NPIX_HALO][CG];   // 18 KB

    const int bid  = blockIdx.x;
    const int g    = bid & 7;
    const int tile = bid >> 3;
    const int tj   = tile % NT;
    const int ti   = (tile / NT) % NT;
    const int b    = tile / (NT * NT);

    const int t  = threadIdx.x;
    const int c  = t & 31;
    const int p0 = t >> 5;

    // stage k,v halo with float4: 8 lanes cover one pixel's 32 channels
    const int c4 = t & 7, pp = t >> 3;   // pp: 0..31
    const int h0 = ti * TILE - PAD, w0 = tj * TILE - PAD;
#pragma unroll
    for (int it = 0; it < 5; ++it) {
        const int hp = pp + it * 32;
        if (hp < NPIX_HALO) {
            const int hi = hp / HT, hj = hp % HT;
            const int gh = h0 + hi, gw = w0 + hj;
            float4 kv = make_float4(0.f, 0.f, 0.f, 0.f);
            float4 vv = kv;
            if (gh >= 0 && gh < TH && gw >= 0 && gw < TW) {
                const size_t off = (((size_t)b * TH + gh) * TW + gw) * TC + g * CG + c4 * 4;
                kv = *(const float4*)(km + off);
                vv = *(const float4*)(vm + off);
            }
            *(float4*)&ks[hp][c4 * 4] = kv;
            *(float4*)&vs[hp][c4 * 4] = vv;
        }
    }

    // q (already *log2e) for this thread's 8 interior pixels (column p0)
    float qreg[8];
#pragma unroll
    for (int ii = 0; ii < 8; ++ii) {
        const int gh = ti * TILE + ii, gw = tj * TILE + p0;
        qreg[ii] = qm[(((size_t)b * TH + gh) * TW + gw) * TC + g * CG + c];
    }

    // rel row for this channel from global (L1/L2-hot; compiler-managed regs)
    const float* rp = rel + ((size_t)g * CG + c) * 25;
    float relr[25];
#pragma unroll
    for (int i = 0; i < 25; ++i) relr[i] = rp[i];

    __syncthreads();

    // ---- row-streaming attention: each halo row's 5 k/v values loaded once,
    //      scattered into the (up to 5) output pixels whose window covers it.
    float s_[8], a_[8];
#pragma unroll
    for (int ii = 0; ii < 8; ++ii) { s_[ii] = 0.f; a_[ii] = 0.f; }

#pragma unroll
    for (int h = 0; h < HT; ++h) {
        float kr[5], vr[5];
#pragma unroll
        for (int j = 0; j < 5; ++j) {
            kr[j] = ks[h * HT + p0 + j][c];
            vr[j] = vs[h * HT + p0 + j][c];
        }
#pragma unroll
        for (int ii = 0; ii < 8; ++ii) {
            const int di = h - ii;               // compile-time after unroll
            if (di >= 0 && di < 5) {
                const float qv = qreg[ii];
#pragma unroll
                for (int j = 0; j < 5; ++j) {
                    const float e = __builtin_amdgcn_exp2f(qv * (kr[j] + relr[di * 5 + j]));
                    s_[ii] += e;
                    a_[ii] = fmaf(e, vr[j], a_[ii]);
                }
            }
        }
    }

#pragma unroll
    for (int ii = 0; ii < 8; ++ii) {
        const int gh = ti * TILE + ii, gw = tj * TILE + p0;
        out[(((size_t)b * TH + gh) * TW + gw) * TC + g * CG + c] =
            a_[ii] * __builtin_amdgcn_rcpf(s_[ii]);
    }
}

// ---------------- Fallback (ws too small): fused single kernel ----------------
__global__ __launch_bounds__(256, 2)
void attn_conv_full_kernel(const float* __restrict__ x,
                           const float* __restrict__ wq,
                           const float* __restrict__ wk,
                           const float* __restrict__ wv,
                           const float* __restrict__ rel,
                           const float* __restrict__ qemb,
                           float* __restrict__ out) {
    __shared__ float xs[NPIX_HALO][CG];
    __shared__ float ks[NPIX_HALO][CG];
    __shared__ float vs[NPIX_HALO][CG];
    __shared__ float rels[CG][25];

    const int bid  = blockIdx.x;
    const int g    = bid & 7;
    const int tile = bid >> 3;
    const int tj   = tile % NT;
    const int ti   = (tile / NT) % NT;
    const int b    = tile / (NT * NT);

    const int t  = threadIdx.x;
    const int c  = t & 31;
    const int p0 = t >> 5;

    for (int i = t; i < CG * 25; i += 256)
        rels[i / 25][i % 25] = rel[g * CG * 25 + i];

    const int h0 = ti * TILE - PAD, w0 = tj * TILE - PAD;
    for (int it = 0; it < NPIX_HALO / 8; ++it) {
        const int hp = p0 + it * 8;
        const int hi = hp / HT, hj = hp % HT;
        const int gh = h0 + hi, gw = w0 + hj;
        float val = 0.f;
        if (gh >= 0 && gh < TH && gw >= 0 && gw < TW)
            val = x[(((size_t)b * TH + gh) * TW + gw) * TC + g * CG + c];
        xs[hp][c] = val;
    }

    float wqr[CG], wkr[CG], wvr[CG];
    {
        const float* wqp = wq + (size_t)(g * CG + c) * CG;
        const float* wkp = wk + (size_t)(g * CG + c) * CG;
        const float* wvp = wv + (size_t)(g * CG + c) * CG;
#pragma unroll
        for (int i = 0; i < CG; ++i) { wqr[i] = wqp[i]; wkr[i] = wkp[i]; wvr[i] = wvp[i]; }
    }
    const float qe = qemb[g * CG + c];
    __syncthreads();

    for (int it = 0; it < NPIX_HALO / 8; ++it) {
        const int hp = p0 + it * 8;
        const float4* xp = (const float4*)&xs[hp][0];
        float acck = 0.f, accv = 0.f;
#pragma unroll
        for (int i4 = 0; i4 < CG / 4; ++i4) {
            const float4 xv = xp[i4];
            acck += wkr[4*i4+0]*xv.x; accv += wvr[4*i4+0]*xv.x;
            acck += wkr[4*i4+1]*xv.y; accv += wvr[4*i4+1]*xv.y;
            acck += wkr[4*i4+2]*xv.z; accv += wvr[4*i4+2]*xv.z;
            acck += wkr[4*i4+3]*xv.w; accv += wvr[4*i4+3]*xv.w;
        }
        ks[hp][c] = acck;
        vs[hp][c] = accv;
    }

    float qreg[8];
#pragma unroll
    for (int it = 0; it < 8; ++it) {
        const int hp = (it + PAD) * HT + (p0 + PAD);
        const float4* xp = (const float4*)&xs[hp][0];
        float acc = qe;
#pragma unroll
        for (int i4 = 0; i4 < CG / 4; ++i4) {
            const float4 xv = xp[i4];
            acc += wqr[4*i4+0]*xv.x + wqr[4*i4+1]*xv.y
                 + wqr[4*i4+2]*xv.z + wqr[4*i4+3]*xv.w;
        }
        qreg[it] = acc;
    }
    __syncthreads();

    float relr[25];
#pragma unroll
    for (int i = 0; i < 25; ++i) relr[i] = rels[c][i];

#pragma unroll
    for (int it = 0; it < 8; ++it) {
        const float qv = qreg[it] * LOG2E;
        float s = 0.f, acc = 0.f;
#pragma unroll
        for (int di = 0; di < 5; ++di)
#pragma unroll
            for (int dj = 0; dj < 5; ++dj) {
                const int hp = (it + di) * HT + (p0 + dj);
                const float e = __builtin_amdgcn_exp2f(qv * (ks[hp][c] + relr[di * 5 + dj]));
                s   += e;
                acc  = fmaf(e, vs[hp][c], acc);
            }
        const int gh = ti * TILE + it, gw = tj * TILE + p0;
        out[(((size_t)b * TH + gh) * TW + gw) * TC + g * CG + c] =
            acc * __builtin_amdgcn_rcpf(s);
    }
}

extern "C" void kernel_launch(void* const* d_in, const int* in_sizes, int n_in,
                              void* d_out, int out_size, void* d_ws, size_t ws_size,
                              hipStream_t stream) {
    const float* x    = (const float*)d_in[0];
    const float* wq   = (const float*)d_in[1];
    const float* wk   = (const float*)d_in[2];
    const float* wv   = (const float*)d_in[3];
    const float* rel  = (const float*)d_in[4];
    const float* qemb = (const float*)d_in[5];
    float* out = (float*)d_out;

    const size_t npix_tot  = (size_t)TB * TH * TW;        // 12544
    const size_t map_elems = npix_tot * TC;               // 3,211,264
    const size_t need = 3 * map_elems * sizeof(float);    // ~38.6 MB

    if (ws_size >= need) {
        float* qmap = (float*)d_ws;
        float* kmap = qmap + map_elems;
        float* vmap = kmap + map_elems;
        hipLaunchKernelGGL(qkv_kernel, dim3(npix_tot / PPB), dim3(256), 0, stream,
                           x, wq, wk, wv, qemb, qmap, kmap, vmap);
        hipLaunchKernelGGL(attn_kernel, dim3(TB * NT * NT * G), dim3(256), 0, stream,
                           qmap, kmap, vmap, rel, out);
    } else {
        hipLaunchKernelGGL(attn_conv_full_kernel, dim3(TB * NT * NT * G), dim3(256), 0, stream,
                           x, wq, wk, wv, rel, qemb, out);
    }
}